// Round 1
// baseline (247.598 us; speedup 1.0000x reference)
//
#include <hip/hip_runtime.h>
#include <math.h>

#define D 2048
#define NTHREADS 256
#define VEC_PER_THREAD 2   // 2 float4 = 8 floats per thread; 256*8 = 2048 = D

// ws layout (floats): [0..D-1] inv_std = 1/(sqrt(max(ema_sq-mu^2,1e-4))+1e-5)
//                     [D+0] tau, [D+1] sigma, [D+2] w, [D+3] surp_ema, [D+4] 1/max(||ema_out||,1e-12)

__global__ __launch_bounds__(NTHREADS) void precompute_kernel(
    const float* __restrict__ ema_mean,
    const float* __restrict__ ema_sq,
    const float* __restrict__ ema_out,
    const float* __restrict__ surp_ema,
    const float* __restrict__ log_tau,
    const float* __restrict__ log_sigma,
    const float* __restrict__ log_w_raw,
    float* __restrict__ ws) {
  const int t = threadIdx.x;
  float eo2 = 0.f;
#pragma unroll
  for (int i = 0; i < D / NTHREADS; ++i) {
    const int d = t + i * NTHREADS;
    const float mu = ema_mean[d];
    const float var = fmaxf(ema_sq[d] - mu * mu, 1e-4f);
    ws[d] = 1.0f / (sqrtf(var) + 1e-5f);
    const float e = ema_out[d];
    eo2 += e * e;
  }
  // reduce eo2 across the block (4 waves of 64)
  __shared__ float s[4];
#pragma unroll
  for (int off = 32; off > 0; off >>= 1) eo2 += __shfl_down(eo2, off);
  if ((t & 63) == 0) s[t >> 6] = eo2;
  __syncthreads();
  if (t == 0) {
    const float norm_e = sqrtf(s[0] + s[1] + s[2] + s[3]);
    ws[D + 0] = expf(log_tau[0]);
    ws[D + 1] = log1pf(expf(log_sigma[0]));  // softplus
    ws[D + 2] = log1pf(expf(log_w_raw[0]));  // softplus
    ws[D + 3] = surp_ema[0];
    ws[D + 4] = 1.0f / fmaxf(norm_e, 1e-12f);
  }
}

__global__ __launch_bounds__(NTHREADS) void gate_kernel(
    const float* __restrict__ x,
    const float* __restrict__ ema_mean,
    const float* __restrict__ ema_out,
    const float* __restrict__ ws,
    float* __restrict__ out) {
  const int row = blockIdx.x;
  const int t = threadIdx.x;
  const float* __restrict__ xr = x + (size_t)row * D;
  float* __restrict__ outr = out + (size_t)row * D;

  const float tau    = ws[D + 0];
  const float sigma  = ws[D + 1];
  const float w      = ws[D + 2];
  const float surp_e = ws[D + 3];
  const float inv_ne = ws[D + 4];

  const float kC = 0.7978845608028654f;  // sqrt(2/pi)

  float o[VEC_PER_THREAD * 4];
  float sum_absz = 0.f, sum_o2 = 0.f, sum_dot = 0.f;

#pragma unroll
  for (int i = 0; i < VEC_PER_THREAD; ++i) {
    const int v = t + i * NTHREADS;  // float4 index within the row
    const float4 xv = ((const float4*)xr)[v];
    const float4 mv = ((const float4*)ema_mean)[v];
    const float4 iv = ((const float4*)ws)[v];
    const float4 ev = ((const float4*)ema_out)[v];
    const float xs[4] = {xv.x, xv.y, xv.z, xv.w};
    const float ms[4] = {mv.x, mv.y, mv.z, mv.w};
    const float is[4] = {iv.x, iv.y, iv.z, iv.w};
    const float es[4] = {ev.x, ev.y, ev.z, ev.w};
#pragma unroll
    for (int j = 0; j < 4; ++j) {
      const float xx = xs[j];
      const float inner = kC * (xx + 0.044715f * xx * xx * xx);
      const float g = 0.5f * xx * (1.0f + tanhf(inner));
      o[i * 4 + j] = g;
      sum_absz += fabsf((xx - ms[j]) * is[j]);
      sum_o2   += g * g;
      sum_dot  += g * es[j];
    }
  }

  // three-way block reduction: wave64 shuffle, then 4 partials via LDS
#pragma unroll
  for (int off = 32; off > 0; off >>= 1) {
    sum_absz += __shfl_down(sum_absz, off);
    sum_o2   += __shfl_down(sum_o2, off);
    sum_dot  += __shfl_down(sum_dot, off);
  }
  __shared__ float sred[3][4];
  const int wave = t >> 6;
  if ((t & 63) == 0) {
    sred[0][wave] = sum_absz;
    sred[1][wave] = sum_o2;
    sred[2][wave] = sum_dot;
  }
  __syncthreads();
  const float tot_absz = sred[0][0] + sred[0][1] + sred[0][2] + sred[0][3];
  const float tot_o2   = sred[1][0] + sred[1][1] + sred[1][2] + sred[1][3];
  const float tot_dot  = sred[2][0] + sred[2][1] + sred[2][2] + sred[2][3];

  const float mean_absz = tot_absz * (1.0f / (float)D);
  const float surp_raw  = tanhf(sigma * mean_absz);
  const float surp_mod  = fmaxf(surp_raw - surp_e, 0.0f);
  const float inv_no    = 1.0f / fmaxf(sqrtf(tot_o2), 1e-12f);
  float cs = tot_dot * inv_no * inv_ne;
  cs = fminf(fmaxf(cs, -1.0f), 1.0f);
  const float gate = expf(-tau * cs) * (1.0f + w * surp_mod);

#pragma unroll
  for (int i = 0; i < VEC_PER_THREAD; ++i) {
    const int v = t + i * NTHREADS;
    float4 r;
    r.x = o[i * 4 + 0] * gate;
    r.y = o[i * 4 + 1] * gate;
    r.z = o[i * 4 + 2] * gate;
    r.w = o[i * 4 + 3] * gate;
    ((float4*)outr)[v] = r;
  }
}

extern "C" void kernel_launch(void* const* d_in, const int* in_sizes, int n_in,
                              void* d_out, int out_size, void* d_ws, size_t ws_size,
                              hipStream_t stream) {
  const float* x        = (const float*)d_in[0];
  const float* ema_mean = (const float*)d_in[1];
  const float* ema_sq   = (const float*)d_in[2];
  const float* ema_out  = (const float*)d_in[3];
  const float* surp_ema = (const float*)d_in[4];
  const float* log_tau  = (const float*)d_in[5];
  const float* log_sig  = (const float*)d_in[6];
  const float* log_wr   = (const float*)d_in[7];
  float* out = (float*)d_out;
  float* ws  = (float*)d_ws;

  const int rows = in_sizes[0] / D;  // B*T = 16384

  precompute_kernel<<<1, NTHREADS, 0, stream>>>(
      ema_mean, ema_sq, ema_out, surp_ema, log_tau, log_sig, log_wr, ws);
  gate_kernel<<<rows, NTHREADS, 0, stream>>>(x, ema_mean, ema_out, ws, out);
}

// Round 3
// 244.681 us; speedup vs baseline: 1.0119x; 1.0119x over previous
//
#include <hip/hip_runtime.h>
#include <math.h>

#define D 2048
#define NT 256   // 256 threads * 8 floats = 2048 = D, one row per block

typedef float floatx4 __attribute__((ext_vector_type(4)));

__global__ __launch_bounds__(NT) void fused_gate_kernel(
    const float* __restrict__ x,
    const float* __restrict__ ema_mean,
    const float* __restrict__ ema_sq,
    const float* __restrict__ ema_out,
    const float* __restrict__ surp_ema,
    const float* __restrict__ log_tau,
    const float* __restrict__ log_sigma,
    const float* __restrict__ log_w_raw,
    float* __restrict__ out) {
  const int row = blockIdx.x;
  const int t = threadIdx.x;
  const float* __restrict__ xr = x + (size_t)row * D;
  float* __restrict__ outr = out + (size_t)row * D;

  // per-thread scalar transforms (all lanes same value, broadcast loads; cheap)
  const float tau    = __expf(log_tau[0]);
  const float sigma  = log1pf(__expf(log_sigma[0]));   // softplus
  const float w      = log1pf(__expf(log_w_raw[0]));   // softplus
  const float surp_e = surp_ema[0];

  // gelu-tanh via sigmoid: g = x * rcp(1 + exp(-2*kC*(x + 0.044715 x^3)))
  const float c1 = -2.0f * 0.7978845608028654f;            // -2*sqrt(2/pi)
  const float c2 = c1 * 0.044715f;

  float o[8];
  float s_absz = 0.f, s_o2 = 0.f, s_dot = 0.f, s_e2 = 0.f;

#pragma unroll
  for (int i = 0; i < 2; ++i) {
    const int v = t + i * NT;  // float4 index within row
    const floatx4 xv = __builtin_nontemporal_load((const floatx4*)xr + v);
    const floatx4 mv = ((const floatx4*)ema_mean)[v];
    const floatx4 qv = ((const floatx4*)ema_sq)[v];
    const floatx4 ev = ((const floatx4*)ema_out)[v];
#pragma unroll
    for (int j = 0; j < 4; ++j) {
      const float xx = xv[j];
      // gelu
      const float x2 = xx * xx;
      const float u2 = xx * fmaf(c2, x2, c1);           // -2*inner
      const float g  = xx * __builtin_amdgcn_rcpf(1.0f + __expf(u2));
      o[i * 4 + j] = g;
      // z-score |.|
      const float mu  = mv[j];
      const float var = fmaxf(fmaf(-mu, mu, qv[j]), 1e-4f);
      const float inv = __builtin_amdgcn_rsqf(var);     // ~= 1/(std+1e-5)
      s_absz += fabsf((xx - mu) * inv);
      // norms / dot
      const float e = ev[j];
      s_o2  = fmaf(g, g, s_o2);
      s_dot = fmaf(g, e, s_dot);
      s_e2  = fmaf(e, e, s_e2);
    }
  }

  // 4-way fused block reduction: wave64 shuffle, then 4 wave partials via LDS
#pragma unroll
  for (int off = 32; off > 0; off >>= 1) {
    s_absz += __shfl_down(s_absz, off);
    s_o2   += __shfl_down(s_o2, off);
    s_dot  += __shfl_down(s_dot, off);
    s_e2   += __shfl_down(s_e2, off);
  }
  __shared__ float sred[4][4];
  const int wave = t >> 6;
  if ((t & 63) == 0) {
    sred[0][wave] = s_absz;
    sred[1][wave] = s_o2;
    sred[2][wave] = s_dot;
    sred[3][wave] = s_e2;
  }
  __syncthreads();
  const float tot_absz = sred[0][0] + sred[0][1] + sred[0][2] + sred[0][3];
  const float tot_o2   = sred[1][0] + sred[1][1] + sred[1][2] + sred[1][3];
  const float tot_dot  = sred[2][0] + sred[2][1] + sred[2][2] + sred[2][3];
  const float tot_e2   = sred[3][0] + sred[3][1] + sred[3][2] + sred[3][3];

  const float mean_absz = tot_absz * (1.0f / (float)D);
  const float surp_raw  = tanhf(sigma * mean_absz);     // once per row, keep libm
  const float surp_mod  = fmaxf(surp_raw - surp_e, 0.0f);
  const float inv_no = __builtin_amdgcn_rsqf(fmaxf(tot_o2, 1e-24f));
  const float inv_ne = __builtin_amdgcn_rsqf(fmaxf(tot_e2, 1e-24f));
  float cs = tot_dot * inv_no * inv_ne;
  cs = fminf(fmaxf(cs, -1.0f), 1.0f);
  const float gate = __expf(-tau * cs) * (1.0f + w * surp_mod);

#pragma unroll
  for (int i = 0; i < 2; ++i) {
    const int v = t + i * NT;
    floatx4 r;
    r[0] = o[i * 4 + 0] * gate;
    r[1] = o[i * 4 + 1] * gate;
    r[2] = o[i * 4 + 2] * gate;
    r[3] = o[i * 4 + 3] * gate;
    __builtin_nontemporal_store(r, (floatx4*)outr + v);
  }
}

extern "C" void kernel_launch(void* const* d_in, const int* in_sizes, int n_in,
                              void* d_out, int out_size, void* d_ws, size_t ws_size,
                              hipStream_t stream) {
  const float* x        = (const float*)d_in[0];
  const float* ema_mean = (const float*)d_in[1];
  const float* ema_sq   = (const float*)d_in[2];
  const float* ema_out  = (const float*)d_in[3];
  const float* surp_ema = (const float*)d_in[4];
  const float* log_tau  = (const float*)d_in[5];
  const float* log_sig  = (const float*)d_in[6];
  const float* log_wr   = (const float*)d_in[7];
  float* out = (float*)d_out;

  const int rows = in_sizes[0] / D;  // B*T = 16384

  fused_gate_kernel<<<rows, NT, 0, stream>>>(
      x, ema_mean, ema_sq, ema_out, surp_ema, log_tau, log_sig, log_wr, out);
}

// Round 4
// 244.629 us; speedup vs baseline: 1.0121x; 1.0002x over previous
//
#include <hip/hip_runtime.h>
#include <math.h>

#define D 2048
#define NT 256            // 4 waves per block, one ROW per wave
#define ROWS_PER_BLOCK 4
#define V_PER_LANE 8      // 64 lanes * 8 float4 = 512 float4 = 2048 floats = D

typedef float floatx4 __attribute__((ext_vector_type(4)));

__global__ __launch_bounds__(NT) void fused_gate_kernel(
    const float* __restrict__ x,
    const float* __restrict__ ema_mean,
    const float* __restrict__ ema_sq,
    const float* __restrict__ ema_out,
    const float* __restrict__ surp_ema,
    const float* __restrict__ log_tau,
    const float* __restrict__ log_sigma,
    const float* __restrict__ log_w_raw,
    float* __restrict__ out) {
  const int t = threadIdx.x;
  const int lane = t & 63;
  const int wave = t >> 6;
  const int row = blockIdx.x * ROWS_PER_BLOCK + wave;

  const float* __restrict__ xr = x + (size_t)row * D;
  float* __restrict__ outr = out + (size_t)row * D;

  // scalar transforms (uniform; scalar-unit loads)
  const float tau    = __expf(log_tau[0]);
  const float sigma  = log1pf(__expf(log_sigma[0]));   // softplus
  const float w      = log1pf(__expf(log_w_raw[0]));   // softplus
  const float surp_e = surp_ema[0];

  // gelu-tanh via sigmoid: g = x * rcp(1 + exp(x*(c1 + c2*x^2)))
  const float c1 = -2.0f * 0.7978845608028654f;        // -2*sqrt(2/pi)
  const float c2 = c1 * 0.044715f;

  float o[V_PER_LANE * 4];
  float s_absz = 0.f, s_o2 = 0.f, s_dot = 0.f, s_e2 = 0.f;

#pragma unroll
  for (int i = 0; i < V_PER_LANE; ++i) {
    const int v = lane + i * 64;  // float4 index within the row
    const floatx4 xv = __builtin_nontemporal_load((const floatx4*)xr + v);
    const floatx4 mv = ((const floatx4*)ema_mean)[v];
    const floatx4 qv = ((const floatx4*)ema_sq)[v];
    const floatx4 ev = ((const floatx4*)ema_out)[v];
#pragma unroll
    for (int j = 0; j < 4; ++j) {
      const float xx = xv[j];
      const float x2 = xx * xx;
      const float u2 = xx * fmaf(c2, x2, c1);           // -2*inner
      const float g  = xx * __builtin_amdgcn_rcpf(1.0f + __expf(u2));
      o[i * 4 + j] = g;
      const float mu  = mv[j];
      const float var = fmaxf(fmaf(-mu, mu, qv[j]), 1e-4f);
      const float inv = __builtin_amdgcn_rsqf(var);     // ~= 1/(std+1e-5)
      s_absz += fabsf((xx - mu) * inv);
      const float e = ev[j];
      s_o2  = fmaf(g, g, s_o2);
      s_dot = fmaf(g, e, s_dot);
      s_e2  = fmaf(e, e, s_e2);
    }
  }

  // in-wave butterfly reduction: every lane ends with the row totals
#pragma unroll
  for (int off = 32; off > 0; off >>= 1) {
    s_absz += __shfl_xor(s_absz, off);
    s_o2   += __shfl_xor(s_o2, off);
    s_dot  += __shfl_xor(s_dot, off);
    s_e2   += __shfl_xor(s_e2, off);
  }

  const float mean_absz = s_absz * (1.0f / (float)D);
  const float surp_raw  = tanhf(sigma * mean_absz);     // once per row
  const float surp_mod  = fmaxf(surp_raw - surp_e, 0.0f);
  const float inv_no = __builtin_amdgcn_rsqf(fmaxf(s_o2, 1e-24f));
  const float inv_ne = __builtin_amdgcn_rsqf(fmaxf(s_e2, 1e-24f));
  float cs = s_dot * inv_no * inv_ne;
  cs = fminf(fmaxf(cs, -1.0f), 1.0f);
  const float gate = __expf(-tau * cs) * (1.0f + w * surp_mod);

#pragma unroll
  for (int i = 0; i < V_PER_LANE; ++i) {
    const int v = lane + i * 64;
    floatx4 r;
    r[0] = o[i * 4 + 0] * gate;
    r[1] = o[i * 4 + 1] * gate;
    r[2] = o[i * 4 + 2] * gate;
    r[3] = o[i * 4 + 3] * gate;
    __builtin_nontemporal_store(r, (floatx4*)outr + v);
  }
}

extern "C" void kernel_launch(void* const* d_in, const int* in_sizes, int n_in,
                              void* d_out, int out_size, void* d_ws, size_t ws_size,
                              hipStream_t stream) {
  const float* x        = (const float*)d_in[0];
  const float* ema_mean = (const float*)d_in[1];
  const float* ema_sq   = (const float*)d_in[2];
  const float* ema_out  = (const float*)d_in[3];
  const float* surp_ema = (const float*)d_in[4];
  const float* log_tau  = (const float*)d_in[5];
  const float* log_sig  = (const float*)d_in[6];
  const float* log_wr   = (const float*)d_in[7];
  float* out = (float*)d_out;

  const int rows = in_sizes[0] / D;  // B*T = 16384
  fused_gate_kernel<<<rows / ROWS_PER_BLOCK, NT, 0, stream>>>(
      x, ema_mean, ema_sq, ema_out, surp_ema, log_tau, log_sig, log_wr, out);
}